// Round 6
// baseline (118.937 us; speedup 1.0000x reference)
//
#include <hip/hip_runtime.h>
#include <hip/hip_bf16.h>
#include <stdint.h>

#define S_TOK 3072
#define E_DIM 1280
#define H_NUM 20
#define D_HEAD 64
#define NSEG 16

typedef __attribute__((ext_vector_type(8))) short short8;
typedef __attribute__((ext_vector_type(4))) float f32x4;

__device__ __forceinline__ unsigned short f2bf(float f){
  union { float f; unsigned int i; } u; u.f = f;
  unsigned int r = u.i + 0x7FFFu + ((u.i >> 16) & 1u);
  return (unsigned short)(r >> 16);
}

__device__ __forceinline__ void gload_lds16(const void* g, void* l){
  __builtin_amdgcn_global_load_lds((__attribute__((address_space(1))) void*)(g),
                                   (__attribute__((address_space(3))) void*)(l), 16, 0, 0);
}

// ---------------- all f32 -> bf16 conversions in one launch ----------------
__global__ void cvt_all(const float* __restrict__ hs,
                        const float* __restrict__ w0, const float* __restrict__ w1,
                        const float* __restrict__ w2, const float* __restrict__ w3,
                        unsigned short* __restrict__ hsb,
                        unsigned short* __restrict__ dqkv, unsigned short* __restrict__ dob,
                        int nHS4, int nW4){
  int i = blockIdx.x * blockDim.x + threadIdx.x;
  const float* src;
  unsigned short* dst;
  size_t sj, dj;
  if (i < nHS4){
    src = hs; dst = hsb; sj = i; dj = i;
  } else {
    int t = i - nHS4;
    int w = t / nW4;
    if (w >= 4) return;
    int j = t - w * nW4;
    src = (w == 0) ? w0 : (w == 1) ? w1 : (w == 2) ? w2 : w3;
    sj = j;
    if (w < 3){ dst = dqkv; dj = (size_t)w * nW4 + j; }
    else      { dst = dob;  dj = j; }
  }
  float4 v = reinterpret_cast<const float4*>(src)[sj];
  ushort4 o;
  o.x = f2bf(v.x); o.y = f2bf(v.y); o.z = f2bf(v.z); o.w = f2bf(v.w);
  reinterpret_cast<ushort4*>(dst)[dj] = o;
}

// ---------------- GEMM: C = A[M,K] @ B[N,K]^T  (bf16 in, f32 acc) ----------------
// 256x256 tile, 8 waves (2Mx4N), wave-tile 128x64 (acc[8][4]): 32 MFMA per
// 12 ds_read_b128 -> 2.67x the LDS-read intensity of the 128^2 structure.
// BK=32, ring-3 K-tile buffers (96 KB LDS), counted vmcnt(4) (never 0
// mid-loop), phase-split MFMA with setprio, 0-conflict swizzle (r5-verified).
// MODE 0: QKV fused (N=3E): LDS-staged coalesced scatter to q/k/v [H][S][D]
// MODE 1: out proj (N=E): f32 out [S][E] + bias
template<int MODE>
__global__ __launch_bounds__(512, 2) void gemm256(
    const unsigned short* __restrict__ A,
    const unsigned short* __restrict__ B,
    const float* __restrict__ bias0,
    const float* __restrict__ bias1,
    unsigned short* __restrict__ Oq,
    unsigned short* __restrict__ Ok,
    unsigned short* __restrict__ Ov,
    float* __restrict__ Of,
    int M, int N, int K)
{
  // 3 slots x [A 256x32 | B 256x32] shorts = 3 x 16384 shorts = 96 KB
  __shared__ __align__(16) unsigned short SH[49152];

  const int nbn = N >> 8;
  const int bm = blockIdx.x / nbn;
  const int bn = blockIdx.x % nbn;
  const int row0 = bm << 8;
  const int col0 = bn << 8;

  const int tid  = threadIdx.x;
  const int lane = tid & 63;
  const int w    = tid >> 6;
  const int wm   = w >> 2;        // 0..1  (M half)
  const int wn   = w & 3;         // 0..3  (N quarter)

  const f32x4 fz = {0.f, 0.f, 0.f, 0.f};
  f32x4 acc[8][4];
#pragma unroll
  for (int m = 0; m < 8; ++m)
#pragma unroll
    for (int n = 0; n < 4; ++n) acc[m][n] = fz;

  // stage one K-tile (A 256x32 + B 256x32); 4 gload16/thread.
  // phys slot p of row r holds k-chunk p ^ ((r>>1)&3)  (2-way max -> free)
  auto stage = [&](int sl, int t){
    unsigned short* As = SH + sl * 16384;
    unsigned short* Bs = As + 8192;
    const int k0 = t << 5;
#pragma unroll
    for (int i = 0; i < 2; ++i){
      int s = i*512 + tid;          // 0..1023 16B slots
      int r = s >> 2, p = s & 3;
      int ks = p ^ ((r >> 1) & 3);
      gload_lds16(A + (size_t)(row0 + r)*K + k0 + ks*8, &As[s*8]);
    }
#pragma unroll
    for (int i = 0; i < 2; ++i){
      int s = i*512 + tid;
      int r = s >> 2, p = s & 3;
      int ks = p ^ ((r >> 1) & 3);
      gload_lds16(B + (size_t)(col0 + r)*K + k0 + ks*8, &Bs[s*8]);
    }
  };

  const int nk = K >> 5;            // 40
  stage(0, 0);
  stage(1, 1);
  int sl = 0;
  for (int t = 0; t < nk; ++t){
    if (t == nk - 1) asm volatile("s_waitcnt vmcnt(0)" ::: "memory");
    else             asm volatile("s_waitcnt vmcnt(4)" ::: "memory");
    __builtin_amdgcn_s_barrier();
    if (t + 2 < nk){
      int ns = sl + 2; if (ns >= 3) ns -= 3;
      stage(ns, t + 2);             // targets slot of tile t-1 (reads done)
    }
    const unsigned short* As = SH + sl * 16384;
    const unsigned short* Bs = As + 8192;

    short8 bf[4];
#pragma unroll
    for (int n = 0; n < 4; ++n){
      int rb = wn*64 + n*16 + (lane & 15);
      bf[n] = *reinterpret_cast<const short8*>(&Bs[rb*32 + (((lane >> 4) ^ ((rb >> 1) & 3)))*8]);
    }
#pragma unroll
    for (int mh = 0; mh < 2; ++mh){
      short8 af[4];
#pragma unroll
      for (int m = 0; m < 4; ++m){
        int ra = wm*128 + mh*64 + m*16 + (lane & 15);
        af[m] = *reinterpret_cast<const short8*>(&As[ra*32 + (((lane >> 4) ^ ((ra >> 1) & 3)))*8]);
      }
      __builtin_amdgcn_s_setprio(1);
#pragma unroll
      for (int m = 0; m < 4; ++m)
#pragma unroll
        for (int n = 0; n < 4; ++n)
          acc[mh*4 + m][n] = __builtin_amdgcn_mfma_f32_16x16x32_bf16(af[m], bf[n], acc[mh*4 + m][n], 0, 0, 0);
      __builtin_amdgcn_s_setprio(0);
      if (mh == 0) __builtin_amdgcn_s_barrier();   // mid-tile convoy
    }
    ++sl; if (sl >= 3) sl = 0;
  }
  __syncthreads();   // drain all LDS reads before epilogue reuses SH

  if (MODE == 0){
    // coalesced scatter epilogue: two 128-row phases staged in LDS
    unsigned short* Cs = SH;
    const int CSTR = 264;                  // 128 x 264 = 33792 shorts <= 49152
    const int mat = col0 / E_DIM;          // tile-uniform (1280 % 256 == 0)
    const int cc0 = col0 - mat * E_DIM;
    unsigned short* dst = (mat == 0) ? Oq : ((mat == 1) ? Ok : Ov);
    float bb[4];
#pragma unroll
    for (int n = 0; n < 4; ++n){
      int cc = cc0 + wn*64 + n*16 + (lane & 15);
      bb[n] = (mat == 0) ? bias0[cc] : (mat == 2 ? bias1[cc] : 0.0f);
    }
#pragma unroll
    for (int ph = 0; ph < 2; ++ph){
      if (wm == ph){
#pragma unroll
        for (int m = 0; m < 8; ++m)
#pragma unroll
          for (int n = 0; n < 4; ++n)
#pragma unroll
            for (int j = 0; j < 4; ++j){
              int rr = m*16 + (lane >> 4)*4 + j;          // 0..127
              int c  = wn*64 + n*16 + (lane & 15);        // 0..255
              Cs[rr*CSTR + c] = f2bf(acc[m][n][j] + bb[n]);
            }
      }
      __syncthreads();
#pragma unroll
      for (int i = 0; i < 8; ++i){
        int tk  = i*512 + tid;          // 4096 tasks = 4 head-panels x 128r x 8sl
        int p   = tk >> 10;
        int idx = tk & 1023;
        int rr  = idx >> 3, sq = idx & 7;
        short8 vv = *reinterpret_cast<const short8*>(&Cs[rr*CSTR + p*64 + sq*8]);
        int gr = row0 + ph*128 + rr;
        int hh = (cc0 >> 6) + p;
        *reinterpret_cast<short8*>(&dst[((size_t)hh * S_TOK + gr) * D_HEAD + sq*8]) = vv;
      }
      __syncthreads();
    }
  } else {
#pragma unroll
    for (int m = 0; m < 8; ++m)
#pragma unroll
      for (int n = 0; n < 4; ++n){
        int c = col0 + wn*64 + n*16 + (lane & 15);
        float b = bias0[c];
#pragma unroll
        for (int j = 0; j < 4; ++j){
          int r = row0 + wm*128 + m*16 + (lane >> 4)*4 + j;
          Of[(size_t)r * E_DIM + c] = acc[m][n][j] + b;
        }
      }
  }
}

// ---------------- block-diagonal attention ----------------
// grid = H*NSEG*3 blocks of 256 threads (4 waves x 16 Q-rows = 64 rows/block).
#define VSTR 200
#define PSTR 72
__global__ __launch_bounds__(256, 3) void attn_kernel(
    const unsigned short* __restrict__ Q,
    const unsigned short* __restrict__ Kb,
    const unsigned short* __restrict__ V,
    const int* __restrict__ cu,
    unsigned short* __restrict__ O)
{
  __shared__ __align__(16) unsigned short Vt[64*VSTR];     // [d][k-row]
  __shared__ __align__(16) unsigned short Pw[4][16][PSTR]; // per-wave scratch

  const int bid  = blockIdx.x;
  const int unit = bid / 3;
  const int third= bid - unit*3;
  const int h    = unit >> 4;
  const int seg  = unit & 15;
  const int s0   = cu[seg];
  const int L    = cu[seg + 1] - s0;
  if (L <= 0) return;

  const int tid  = threadIdx.x;
  const int lane = tid & 63;
  const int w    = tid >> 6;
  const int row0g = third*64 + w*16;

  const unsigned short* qh = Q  + (size_t)h * S_TOK * D_HEAD;
  const unsigned short* kh = Kb + (size_t)h * S_TOK * D_HEAD;
  const unsigned short* vh = V  + (size_t)h * S_TOK * D_HEAD;

#pragma unroll
  for (int i = 0; i < 6; ++i){
    int task = i*256 + tid;            // 1536 tasks = 192 rows x 8 d-groups
    int sr   = task % 192;
    int grp  = task / 192;
    int svr  = s0 + (sr < L ? sr : L - 1);
    short8 vv = *reinterpret_cast<const short8*>(vh + (size_t)svr*64 + grp*8);
#pragma unroll
    for (int j = 0; j < 8; ++j) Vt[(grp*8 + j)*VSTR + sr] = (unsigned short)vv[j];
  }

  short8 qf[2];
#pragma unroll
  for (int kk = 0; kk < 2; ++kk){
    int r  = row0g + (lane & 15);
    int sr = s0 + (r < L ? r : L - 1);
    qf[kk] = *reinterpret_cast<const short8*>(qh + (size_t)sr*64 + kk*32 + (lane >> 4)*8);
  }

  __syncthreads();

  const f32x4 fz = {0.f, 0.f, 0.f, 0.f};
  const float SCL = 0.125f * 1.44269504088896f;

  f32x4 sacc[12];
#pragma unroll
  for (int nt = 0; nt < 12; ++nt) sacc[nt] = fz;

#pragma unroll
  for (int nt = 0; nt < 12; ++nt){
    int rb = nt*16 + (lane & 15);
    int sr = s0 + (rb < L ? rb : L - 1);
    const unsigned short* kr = kh + (size_t)sr*64 + (lane >> 4)*8;
    short8 kf0 = *reinterpret_cast<const short8*>(kr);
    short8 kf1 = *reinterpret_cast<const short8*>(kr + 32);
    sacc[nt] = __builtin_amdgcn_mfma_f32_16x16x32_bf16(qf[0], kf0, sacc[nt], 0, 0, 0);
    sacc[nt] = __builtin_amdgcn_mfma_f32_16x16x32_bf16(qf[1], kf1, sacc[nt], 0, 0, 0);
  }

  float rinv[4];
#pragma unroll
  for (int j = 0; j < 4; ++j){
    float mx = -1e30f;
#pragma unroll
    for (int nt = 0; nt < 12; ++nt){
      int c = nt*16 + (lane & 15);
      float vv = (c < L) ? sacc[nt][j] : -1e30f;
      sacc[nt][j] = vv;
      mx = fmaxf(mx, vv);
    }
    mx = fmaxf(mx, __shfl_xor(mx, 1, 64));
    mx = fmaxf(mx, __shfl_xor(mx, 2, 64));
    mx = fmaxf(mx, __shfl_xor(mx, 4, 64));
    mx = fmaxf(mx, __shfl_xor(mx, 8, 64));
    float sum = 0.f;
#pragma unroll
    for (int nt = 0; nt < 12; ++nt){
      float pp = exp2f((sacc[nt][j] - mx) * SCL);
      sacc[nt][j] = pp;
      sum += pp;
    }
    sum += __shfl_xor(sum, 1, 64);
    sum += __shfl_xor(sum, 2, 64);
    sum += __shfl_xor(sum, 4, 64);
    sum += __shfl_xor(sum, 8, 64);
    rinv[j] = 1.0f / sum;
  }

  f32x4 oacc[4];
#pragma unroll
  for (int nt = 0; nt < 4; ++nt) oacc[nt] = fz;

#pragma unroll
  for (int kk = 0; kk < 6; ++kk){
#pragma unroll
    for (int ntl = 0; ntl < 2; ++ntl){
      int nt = kk*2 + ntl;
#pragma unroll
      for (int j = 0; j < 4; ++j)
        Pw[w][(lane >> 4)*4 + j][ntl*16 + (lane & 15)] = f2bf(sacc[nt][j]);
    }
    short8 pf = *reinterpret_cast<const short8*>(&Pw[w][lane & 15][(lane >> 4)*8]);
#pragma unroll
    for (int nt4 = 0; nt4 < 4; ++nt4){
      int dcol = nt4*16 + (lane & 15);
      short8 vf = *reinterpret_cast<const short8*>(&Vt[dcol*VSTR + kk*32 + (lane >> 4)*8]);
      oacc[nt4] = __builtin_amdgcn_mfma_f32_16x16x32_bf16(pf, vf, oacc[nt4], 0, 0, 0);
    }
  }

#pragma unroll
  for (int nt4 = 0; nt4 < 4; ++nt4)
#pragma unroll
    for (int j = 0; j < 4; ++j)
      Pw[w][(lane >> 4)*4 + j][nt4*16 + (lane & 15)] = f2bf(oacc[nt4][j] * rinv[j]);

  {
    int r = lane >> 2;
    int gr = row0g + r;
    if (gr < L){
#pragma unroll
      for (int part = 0; part < 2; ++part){
        int c0 = (lane & 3)*16 + part*8;
        short8 vv = *reinterpret_cast<const short8*>(&Pw[w][r][c0]);
        *reinterpret_cast<short8*>(&O[(size_t)(s0 + gr) * E_DIM + h*64 + c0]) = vv;
      }
    }
  }
}

// ---------------- host launch ----------------
extern "C" void kernel_launch(void* const* d_in, const int* in_sizes, int n_in,
                              void* d_out, int out_size, void* d_ws, size_t ws_size,
                              hipStream_t stream)
{
  const float* hs = (const float*)d_in[0];
  const float* Wq = (const float*)d_in[1];
  const float* bq = (const float*)d_in[2];
  const float* Wk = (const float*)d_in[3];
  const float* Wv = (const float*)d_in[4];
  const float* bv = (const float*)d_in[5];
  const float* Wo = (const float*)d_in[6];
  const float* bo = (const float*)d_in[7];
  const int*   cu = (const int*)d_in[8];
  float* out = (float*)d_out;

  unsigned short* p = (unsigned short*)d_ws;
  unsigned short* hsb  = p; p += (size_t)S_TOK * E_DIM;
  unsigned short* wqkv = p; p += (size_t)3 * E_DIM * E_DIM;
  unsigned short* wob  = p; p += (size_t)E_DIM * E_DIM;
  unsigned short* qb   = p; p += (size_t)S_TOK * E_DIM;
  unsigned short* kb   = p; p += (size_t)S_TOK * E_DIM;
  unsigned short* vb   = p; p += (size_t)S_TOK * E_DIM;
  unsigned short* aob  = p; p += (size_t)S_TOK * E_DIM;

  const int nHS4 = S_TOK * E_DIM / 4;
  const int nW4  = E_DIM * E_DIM / 4;
  const int nCvt = nHS4 + 4 * nW4;
  cvt_all<<<(nCvt + 255) / 256, 256, 0, stream>>>(hs, Wq, Wk, Wv, Wo, hsb, wqkv, wob, nHS4, nW4);

  gemm256<0><<<(S_TOK/256) * (3*E_DIM/256), 512, 0, stream>>>(
      hsb, wqkv, bq, bv, qb, kb, vb, nullptr, S_TOK, 3*E_DIM, E_DIM);

  attn_kernel<<<H_NUM * NSEG * 3, 256, 0, stream>>>(qb, kb, vb, cu, aob);

  gemm256<1><<<(S_TOK/256) * (E_DIM/256), 512, 0, stream>>>(
      aob, wob, bo, nullptr, nullptr, nullptr, nullptr, out, S_TOK, E_DIM, E_DIM);
}